// Round 1
// baseline (1723.096 us; speedup 1.0000x reference)
//
#include <hip/hip_runtime.h>
#include <math.h>

#define D_MODEL 1024
#define NQS 2048
#define NKS 2048
#define BATCH 4

constexpr int BM = 128, BN = 64, BK = 32;

// C[m,n] = sum_k A[m,k]*B[n,k] + bscale*bias[n]   (A:[M,K], B:[N,K], row-major)
__global__ __launch_bounds__(256, 2) void gemm_abt_k(
    const float* __restrict__ A, const float* __restrict__ B,
    const float* __restrict__ bias, float bscale,
    float* __restrict__ C, int M, int N, int K,
    long sAb, long sBb, long sCb, long sBiasb)
{
  __shared__ float As[BK][BM + 4];
  __shared__ float Bs[BK][BN + 4];
  const int bz = blockIdx.z;
  const float* Ab = A + (long)bz * sAb;
  const float* Bb = B + (long)bz * sBb;
  float* Cb = C + (long)bz * sCb;
  const int gm = blockIdx.y * BM;
  const int gn = blockIdx.x * BN;
  const int t = threadIdx.x;
  const int tm = t >> 4, tn = t & 15;

  float acc[8][4];
#pragma unroll
  for (int i = 0; i < 8; ++i)
#pragma unroll
    for (int j = 0; j < 4; ++j) acc[i][j] = 0.f;

  for (int k0 = 0; k0 < K; k0 += BK) {
    // A tile: 128 rows x 32 cols = 1024 float4 loads, 4 per thread
#pragma unroll
    for (int l = 0; l < 4; ++l) {
      int idx = t + l * 256;
      int row = idx >> 3, c4 = idx & 7;
      float4 v = *(const float4*)&Ab[(long)(gm + row) * K + k0 + c4 * 4];
      As[c4 * 4 + 0][row] = v.x;
      As[c4 * 4 + 1][row] = v.y;
      As[c4 * 4 + 2][row] = v.z;
      As[c4 * 4 + 3][row] = v.w;
    }
    // B tile: 64 rows x 32 cols = 512 float4 loads, 2 per thread
#pragma unroll
    for (int l = 0; l < 2; ++l) {
      int idx = t + l * 256;
      int row = idx >> 3, c4 = idx & 7;
      float4 v = *(const float4*)&Bb[(long)(gn + row) * K + k0 + c4 * 4];
      Bs[c4 * 4 + 0][row] = v.x;
      Bs[c4 * 4 + 1][row] = v.y;
      Bs[c4 * 4 + 2][row] = v.z;
      Bs[c4 * 4 + 3][row] = v.w;
    }
    __syncthreads();
#pragma unroll
    for (int kk = 0; kk < BK; ++kk) {
      float4 a0 = *(const float4*)&As[kk][tm * 8];
      float4 a1 = *(const float4*)&As[kk][tm * 8 + 4];
      float4 bv = *(const float4*)&Bs[kk][tn * 4];
      float av[8] = {a0.x, a0.y, a0.z, a0.w, a1.x, a1.y, a1.z, a1.w};
      float bw[4] = {bv.x, bv.y, bv.z, bv.w};
#pragma unroll
      for (int i = 0; i < 8; ++i)
#pragma unroll
        for (int j = 0; j < 4; ++j) acc[i][j] = fmaf(av[i], bw[j], acc[i][j]);
    }
    __syncthreads();
  }
  float bb[4] = {0.f, 0.f, 0.f, 0.f};
  if (bias) {
    const float* bp = bias + (long)bz * sBiasb + gn + tn * 4;
    bb[0] = bp[0] * bscale;
    bb[1] = bp[1] * bscale;
    bb[2] = bp[2] * bscale;
    bb[3] = bp[3] * bscale;
  }
#pragma unroll
  for (int i = 0; i < 8; ++i) {
    float4 o = {acc[i][0] + bb[0], acc[i][1] + bb[1], acc[i][2] + bb[2],
                acc[i][3] + bb[3]};
    *(float4*)&Cb[(long)(gm + tm * 8 + i) * N + gn + tn * 4] = o;
  }
}

// C[m,n] = sum_k A[m,k]*B[k,n]   (A:[M,K], B:[K,N], row-major)
__global__ __launch_bounds__(256, 2) void gemm_ab_k(
    const float* __restrict__ A, const float* __restrict__ B,
    float* __restrict__ C, int M, int N, int K,
    long sAb, long sBb, long sCb)
{
  __shared__ float As[BK][BM + 4];
  __shared__ float Bs[BK][BN + 4];
  const int bz = blockIdx.z;
  const float* Ab = A + (long)bz * sAb;
  const float* Bb = B + (long)bz * sBb;
  float* Cb = C + (long)bz * sCb;
  const int gm = blockIdx.y * BM;
  const int gn = blockIdx.x * BN;
  const int t = threadIdx.x;
  const int tm = t >> 4, tn = t & 15;

  float acc[8][4];
#pragma unroll
  for (int i = 0; i < 8; ++i)
#pragma unroll
    for (int j = 0; j < 4; ++j) acc[i][j] = 0.f;

  for (int k0 = 0; k0 < K; k0 += BK) {
#pragma unroll
    for (int l = 0; l < 4; ++l) {
      int idx = t + l * 256;
      int row = idx >> 3, c4 = idx & 7;
      float4 v = *(const float4*)&Ab[(long)(gm + row) * K + k0 + c4 * 4];
      As[c4 * 4 + 0][row] = v.x;
      As[c4 * 4 + 1][row] = v.y;
      As[c4 * 4 + 2][row] = v.z;
      As[c4 * 4 + 3][row] = v.w;
    }
    // B tile: 32 k-rows x 64 n-cols, direct (coalesced) copy
#pragma unroll
    for (int l = 0; l < 2; ++l) {
      int idx = t + l * 256;          // 0..511
      int row = idx >> 4;             // 0..31 (k)
      int c4 = idx & 15;              // 0..15 (n/4)
      float4 v = *(const float4*)&Bb[(long)(k0 + row) * N + gn + c4 * 4];
      *(float4*)&Bs[row][c4 * 4] = v;
    }
    __syncthreads();
#pragma unroll
    for (int kk = 0; kk < BK; ++kk) {
      float4 a0 = *(const float4*)&As[kk][tm * 8];
      float4 a1 = *(const float4*)&As[kk][tm * 8 + 4];
      float4 bv = *(const float4*)&Bs[kk][tn * 4];
      float av[8] = {a0.x, a0.y, a0.z, a0.w, a1.x, a1.y, a1.z, a1.w};
      float bw[4] = {bv.x, bv.y, bv.z, bv.w};
#pragma unroll
      for (int i = 0; i < 8; ++i)
#pragma unroll
        for (int j = 0; j < 4; ++j) acc[i][j] = fmaf(av[i], bw[j], acc[i][j]);
    }
    __syncthreads();
  }
#pragma unroll
  for (int i = 0; i < 8; ++i) {
    float4 o = {acc[i][0], acc[i][1], acc[i][2], acc[i][3]};
    *(float4*)&Cb[(long)(gm + tm * 8 + i) * N + gn + tn * 4] = o;
  }
}

// In-place: Kp row -> pK = softmax(row); negent[row] = sum pK*log pK
__global__ __launch_bounds__(256) void kstats_k(float* __restrict__ KP,
                                                float* __restrict__ negent)
{
  __shared__ float red[4];
  const long row = blockIdx.x;
  float* x = KP + row * (long)D_MODEL;
  const int t = threadIdx.x;
  float4 v = *(const float4*)&x[t * 4];
  float m = fmaxf(fmaxf(v.x, v.y), fmaxf(v.z, v.w));
  for (int o = 32; o; o >>= 1) m = fmaxf(m, __shfl_xor(m, o));
  if ((t & 63) == 0) red[t >> 6] = m;
  __syncthreads();
  m = fmaxf(fmaxf(red[0], red[1]), fmaxf(red[2], red[3]));
  __syncthreads();
  float4 e = {expf(v.x - m), expf(v.y - m), expf(v.z - m), expf(v.w - m)};
  float s = e.x + e.y + e.z + e.w;
  for (int o = 32; o; o >>= 1) s += __shfl_xor(s, o);
  if ((t & 63) == 0) red[t >> 6] = s;
  __syncthreads();
  s = red[0] + red[1] + red[2] + red[3];
  __syncthreads();
  const float inv = 1.0f / s;
  const float lse = m + logf(s);
  float4 p = {e.x * inv, e.y * inv, e.z * inv, e.w * inv};
  float ne = p.x * (v.x - lse) + p.y * (v.y - lse) + p.z * (v.z - lse) +
             p.w * (v.w - lse);
  for (int o = 32; o; o >>= 1) ne += __shfl_xor(ne, o);
  if ((t & 63) == 0) red[t >> 6] = ne;
  __syncthreads();
  if (t == 0) negent[row] = red[0] + red[1] + red[2] + red[3];
  *(float4*)&x[t * 4] = p;
}

// In-place row softmax over NK=2048 elements
__global__ __launch_bounds__(256) void asoftmax_k(float* __restrict__ S)
{
  __shared__ float red[4];
  const long row = blockIdx.x;
  float* x = S + row * (long)NKS;
  const int t = threadIdx.x;
  float4 v0 = *(const float4*)&x[t * 4];
  float4 v1 = *(const float4*)&x[1024 + t * 4];
  float m = fmaxf(fmaxf(fmaxf(v0.x, v0.y), fmaxf(v0.z, v0.w)),
                  fmaxf(fmaxf(v1.x, v1.y), fmaxf(v1.z, v1.w)));
  for (int o = 32; o; o >>= 1) m = fmaxf(m, __shfl_xor(m, o));
  if ((t & 63) == 0) red[t >> 6] = m;
  __syncthreads();
  m = fmaxf(fmaxf(red[0], red[1]), fmaxf(red[2], red[3]));
  __syncthreads();
  float4 e0 = {expf(v0.x - m), expf(v0.y - m), expf(v0.z - m), expf(v0.w - m)};
  float4 e1 = {expf(v1.x - m), expf(v1.y - m), expf(v1.z - m), expf(v1.w - m)};
  float s = e0.x + e0.y + e0.z + e0.w + e1.x + e1.y + e1.z + e1.w;
  for (int o = 32; o; o >>= 1) s += __shfl_xor(s, o);
  if ((t & 63) == 0) red[t >> 6] = s;
  __syncthreads();
  s = red[0] + red[1] + red[2] + red[3];
  const float inv = 1.0f / s;
  float4 p0 = {e0.x * inv, e0.y * inv, e0.z * inv, e0.w * inv};
  float4 p1 = {e1.x * inv, e1.y * inv, e1.z * inv, e1.w * inv};
  *(float4*)&x[t * 4] = p0;
  *(float4*)&x[1024 + t * 4] = p1;
}

extern "C" void kernel_launch(void* const* d_in, const int* in_sizes, int n_in,
                              void* d_out, int out_size, void* d_ws,
                              size_t ws_size, hipStream_t stream)
{
  const float* Q = (const float*)d_in[0];
  const float* K = (const float*)d_in[1];
  const float* V = (const float*)d_in[2];
  const float* Wq = (const float*)d_in[3];
  const float* bq = (const float*)d_in[4];
  const float* Wk = (const float*)d_in[5];
  const float* bk = (const float*)d_in[6];
  const float* Wv = (const float*)d_in[7];
  const float* bv = (const float*)d_in[8];

  float* out = (float*)d_out;                              // [B,NQ,D]
  float* attn = out + (long)BATCH * NQS * D_MODEL;         // [B,NQ,NK]

  float* Qp = (float*)d_ws;                                // [B*NQ, D]
  float* pK = Qp + (long)BATCH * NQS * D_MODEL;            // [B*NK, D]
  float* Vp = pK + (long)BATCH * NKS * D_MODEL;            // [B*NK, D]
  float* negent = Vp + (long)BATCH * NKS * D_MODEL;        // [B, NK]

  dim3 blk(256);

  // Projections: y = x @ W.T + b ; M=B*N=8192, N=K=1024
  dim3 gp(D_MODEL / BN, (BATCH * NQS) / BM, 1);
  gemm_abt_k<<<gp, blk, 0, stream>>>(Q, Wq, bq, 1.0f, Qp, BATCH * NQS, D_MODEL,
                                     D_MODEL, 0, 0, 0, 0);
  gemm_abt_k<<<gp, blk, 0, stream>>>(K, Wk, bk, 1.0f, pK, BATCH * NKS, D_MODEL,
                                     D_MODEL, 0, 0, 0, 0);
  gemm_abt_k<<<gp, blk, 0, stream>>>(V, Wv, bv, 1.0f, Vp, BATCH * NKS, D_MODEL,
                                     D_MODEL, 0, 0, 0, 0);

  // Kp -> pK (softmax rows) + negent
  kstats_k<<<dim3(BATCH * NKS), blk, 0, stream>>>(pK, negent);

  // scores[b,i,j] = Qp[b,i,:]·pK[b,j,:] - negent[b,j]  (softmax-equivalent)
  dim3 gs(NKS / BN, NQS / BM, BATCH);
  gemm_abt_k<<<gs, blk, 0, stream>>>(Qp, pK, negent, -1.0f, attn, NQS, NKS,
                                     D_MODEL, (long)NQS * D_MODEL,
                                     (long)NKS * D_MODEL, (long)NQS * NKS,
                                     (long)NKS);

  // attn = softmax(scores) in place
  asoftmax_k<<<dim3(BATCH * NQS), blk, 0, stream>>>(attn);

  // out = attn @ Vp
  dim3 go(D_MODEL / BN, NQS / BM, BATCH);
  gemm_ab_k<<<go, blk, 0, stream>>>(attn, Vp, out, NQS, D_MODEL, NKS,
                                    (long)NQS * NKS, (long)NKS * D_MODEL,
                                    (long)NQS * D_MODEL);
}

// Round 2
// 430.812 us; speedup vs baseline: 3.9996x; 3.9996x over previous
//
#include <hip/hip_runtime.h>
#include <math.h>

#define D_MODEL 1024
#define NQS 2048
#define NKS 2048
#define BATCH 4

typedef __attribute__((ext_vector_type(8))) short bf16x8;
typedef __attribute__((ext_vector_type(4))) float f32x4;

#define AS1 __attribute__((address_space(1)))
#define AS3 __attribute__((address_space(3)))

__device__ __forceinline__ unsigned short f2bf(float f) {
  unsigned u = __builtin_bit_cast(unsigned, f);
  u = (u + 0x7FFF + ((u >> 16) & 1)) >> 16;  // RNE
  return (unsigned short)u;
}
__device__ __forceinline__ float bf2f(unsigned short s) {
  return __builtin_bit_cast(float, ((unsigned)s) << 16);
}

// ---------------- fp32 -> bf16 convert (vectorized) ----------------
__global__ __launch_bounds__(256) void cvt_k(const float* __restrict__ src,
                                             short* __restrict__ dst, int n8)
{
  int i = blockIdx.x * 256 + threadIdx.x;
  if (i >= n8) return;
  const float4 a = *(const float4*)&src[(long)i * 8];
  const float4 b = *(const float4*)&src[(long)i * 8 + 4];
  bf16x8 o;
  o[0] = (short)f2bf(a.x); o[1] = (short)f2bf(a.y);
  o[2] = (short)f2bf(a.z); o[3] = (short)f2bf(a.w);
  o[4] = (short)f2bf(b.x); o[5] = (short)f2bf(b.y);
  o[6] = (short)f2bf(b.z); o[7] = (short)f2bf(b.w);
  *(bf16x8*)&dst[(long)i * 8] = o;
}

// ---------------- MFMA GEMM: C = A * B^T (+ bias*bscale per col) ----------
// A: [M,K] bf16 row-major, B: [N,K] bf16 row-major. Writes fp32 (Cf) OR
// bf16 (Cbf). 128x128 tile, 4 waves 2x2, BK=32, global_load_lds staging.
__global__ __launch_bounds__(256, 2) void mfma_abt_k(
    const short* __restrict__ A, const short* __restrict__ B,
    const float* __restrict__ bias, float bscale,
    float* __restrict__ Cf, short* __restrict__ Cbf,
    int N, int K, long sA, long sB, long sC, long sBias)
{
  __shared__ short As[128 * 32];
  __shared__ short Bs[128 * 32];
  const int bz = blockIdx.z;
  const short* Ab = A + (long)bz * sA;
  const short* Bb = B + (long)bz * sB;
  const int gm = blockIdx.y * 128, gn = blockIdx.x * 128;
  const int t = threadIdx.x;
  const int lane = t & 63, w = t >> 6;
  const int wm = w >> 1, wn = w & 1;

  // staging: each wave fills 2 segments of 16 rows x 64B for A and B.
  // LDS dest is wave-uniform base; lane l lands at base + l*16 bytes.
  const int srow = lane >> 2, sq = lane & 3;
  const short* ga0 = Ab + (long)(gm + w * 32 + srow) * K + sq * 8;
  const short* ga1 = Ab + (long)(gm + w * 32 + 16 + srow) * K + sq * 8;
  const short* gb0 = Bb + (long)(gn + w * 32 + srow) * K + sq * 8;
  const short* gb1 = Bb + (long)(gn + w * 32 + 16 + srow) * K + sq * 8;
  short* la0 = As + (w * 2 + 0) * 512;  // 512 shorts = 1024 B segment
  short* la1 = As + (w * 2 + 1) * 512;
  short* lb0 = Bs + (w * 2 + 0) * 512;
  short* lb1 = Bs + (w * 2 + 1) * 512;

  const int frow = lane & 15, fq = lane >> 4;

  f32x4 acc[4][4] = {};

  for (int k0 = 0; k0 < K; k0 += 32) {
    __builtin_amdgcn_global_load_lds((const AS1 void*)(ga0 + k0),
                                     (AS3 void*)la0, 16, 0, 0);
    __builtin_amdgcn_global_load_lds((const AS1 void*)(ga1 + k0),
                                     (AS3 void*)la1, 16, 0, 0);
    __builtin_amdgcn_global_load_lds((const AS1 void*)(gb0 + k0),
                                     (AS3 void*)lb0, 16, 0, 0);
    __builtin_amdgcn_global_load_lds((const AS1 void*)(gb1 + k0),
                                     (AS3 void*)lb1, 16, 0, 0);
    __syncthreads();
    bf16x8 af[4], bfm[4];
#pragma unroll
    for (int mi = 0; mi < 4; ++mi)
      af[mi] = *(const bf16x8*)&As[(wm * 64 + mi * 16 + frow) * 32 + fq * 8];
#pragma unroll
    for (int ni = 0; ni < 4; ++ni)
      bfm[ni] = *(const bf16x8*)&Bs[(wn * 64 + ni * 16 + frow) * 32 + fq * 8];
#pragma unroll
    for (int mi = 0; mi < 4; ++mi)
#pragma unroll
      for (int ni = 0; ni < 4; ++ni)
        acc[mi][ni] = __builtin_amdgcn_mfma_f32_16x16x32_bf16(
            af[mi], bfm[ni], acc[mi][ni], 0, 0, 0);
    __syncthreads();
  }

  float bb[4];
#pragma unroll
  for (int ni = 0; ni < 4; ++ni)
    bb[ni] = bias ? bias[(long)bz * sBias + gn + wn * 64 + ni * 16 + frow] * bscale
                  : 0.f;

  // C/D layout: col = lane&15, row = (lane>>4)*4 + reg   [m89/m91 verified]
#pragma unroll
  for (int mi = 0; mi < 4; ++mi) {
#pragma unroll
    for (int r = 0; r < 4; ++r) {
      const long row = gm + wm * 64 + mi * 16 + fq * 4 + r;
#pragma unroll
      for (int ni = 0; ni < 4; ++ni) {
        const long col = gn + wn * 64 + ni * 16 + frow;
        float v = acc[mi][ni][r] + bb[ni];
        if (Cf) Cf[(long)bz * sC + row * N + col] = v;
        else    Cbf[(long)bz * sC + row * N + col] = (short)f2bf(v);
      }
    }
  }
}

// ---------------- K-stats: bf16 Kp row -> bf16 pK (in place) + negent -----
__global__ __launch_bounds__(256) void kstats_k(short* __restrict__ KP,
                                                float* __restrict__ negent)
{
  __shared__ float red[4];
  const long row = blockIdx.x;
  short* x = KP + row * (long)D_MODEL;
  const int t = threadIdx.x;
  short4 raw = *(const short4*)&x[t * 4];
  float v0 = bf2f((unsigned short)raw.x), v1 = bf2f((unsigned short)raw.y);
  float v2 = bf2f((unsigned short)raw.z), v3 = bf2f((unsigned short)raw.w);
  float m = fmaxf(fmaxf(v0, v1), fmaxf(v2, v3));
  for (int o = 32; o; o >>= 1) m = fmaxf(m, __shfl_xor(m, o));
  if ((t & 63) == 0) red[t >> 6] = m;
  __syncthreads();
  m = fmaxf(fmaxf(red[0], red[1]), fmaxf(red[2], red[3]));
  __syncthreads();
  float e0 = expf(v0 - m), e1 = expf(v1 - m), e2 = expf(v2 - m),
        e3 = expf(v3 - m);
  float s = e0 + e1 + e2 + e3;
  for (int o = 32; o; o >>= 1) s += __shfl_xor(s, o);
  if ((t & 63) == 0) red[t >> 6] = s;
  __syncthreads();
  s = red[0] + red[1] + red[2] + red[3];
  __syncthreads();
  const float inv = 1.0f / s;
  const float lse = m + logf(s);
  float p0 = e0 * inv, p1 = e1 * inv, p2 = e2 * inv, p3 = e3 * inv;
  float ne = p0 * (v0 - lse) + p1 * (v1 - lse) + p2 * (v2 - lse) +
             p3 * (v3 - lse);
  for (int o = 32; o; o >>= 1) ne += __shfl_xor(ne, o);
  if ((t & 63) == 0) red[t >> 6] = ne;
  __syncthreads();
  if (t == 0) negent[row] = red[0] + red[1] + red[2] + red[3];
  short4 pw;
  pw.x = (short)f2bf(p0); pw.y = (short)f2bf(p1);
  pw.z = (short)f2bf(p2); pw.w = (short)f2bf(p3);
  *(short4*)&x[t * 4] = pw;
}

// ---------------- attn softmax: fp32 in place + bf16 copy -----------------
__global__ __launch_bounds__(256) void asoftmax_k(float* __restrict__ S,
                                                  short* __restrict__ Sbf)
{
  __shared__ float red[4];
  const long row = blockIdx.x;
  float* x = S + row * (long)NKS;
  short* y = Sbf + row * (long)NKS;
  const int t = threadIdx.x;
  float4 v0 = *(const float4*)&x[t * 4];
  float4 v1 = *(const float4*)&x[1024 + t * 4];
  float m = fmaxf(fmaxf(fmaxf(v0.x, v0.y), fmaxf(v0.z, v0.w)),
                  fmaxf(fmaxf(v1.x, v1.y), fmaxf(v1.z, v1.w)));
  for (int o = 32; o; o >>= 1) m = fmaxf(m, __shfl_xor(m, o));
  if ((t & 63) == 0) red[t >> 6] = m;
  __syncthreads();
  m = fmaxf(fmaxf(red[0], red[1]), fmaxf(red[2], red[3]));
  __syncthreads();
  float4 e0 = {expf(v0.x - m), expf(v0.y - m), expf(v0.z - m), expf(v0.w - m)};
  float4 e1 = {expf(v1.x - m), expf(v1.y - m), expf(v1.z - m), expf(v1.w - m)};
  float s = e0.x + e0.y + e0.z + e0.w + e1.x + e1.y + e1.z + e1.w;
  for (int o = 32; o; o >>= 1) s += __shfl_xor(s, o);
  if ((t & 63) == 0) red[t >> 6] = s;
  __syncthreads();
  s = red[0] + red[1] + red[2] + red[3];
  const float inv = 1.0f / s;
  float4 p0 = {e0.x * inv, e0.y * inv, e0.z * inv, e0.w * inv};
  float4 p1 = {e1.x * inv, e1.y * inv, e1.z * inv, e1.w * inv};
  *(float4*)&x[t * 4] = p0;
  *(float4*)&x[1024 + t * 4] = p1;
  short4 b0, b1;
  b0.x = (short)f2bf(p0.x); b0.y = (short)f2bf(p0.y);
  b0.z = (short)f2bf(p0.z); b0.w = (short)f2bf(p0.w);
  b1.x = (short)f2bf(p1.x); b1.y = (short)f2bf(p1.y);
  b1.z = (short)f2bf(p1.z); b1.w = (short)f2bf(p1.w);
  *(short4*)&y[t * 4] = b0;
  *(short4*)&y[1024 + t * 4] = b1;
}

// ---------------- Vp [8192,1024] -> Vpt [B][1024][2048] transpose ---------
__global__ __launch_bounds__(256) void transpose_k(const short* __restrict__ src,
                                                   short* __restrict__ dst)
{
  __shared__ short tile[64][68];
  const int j0 = blockIdx.x * 64;  // global Vp row (b*2048 + j)
  const int d0 = blockIdx.y * 64;  // feature col
  const int t = threadIdx.x;
  const int r = t >> 2, c = t & 3;
#pragma unroll
  for (int i = 0; i < 4; ++i)
    *(short4*)&tile[r][c * 16 + i * 4] =
        *(const short4*)&src[(long)(j0 + r) * D_MODEL + d0 + c * 16 + i * 4];
  __syncthreads();
  const long b = j0 >> 11;
  const int jj = j0 & 2047;
#pragma unroll
  for (int i = 0; i < 4; ++i) {
    short4 o;
    o.x = tile[c * 16 + i * 4 + 0][r];
    o.y = tile[c * 16 + i * 4 + 1][r];
    o.z = tile[c * 16 + i * 4 + 2][r];
    o.w = tile[c * 16 + i * 4 + 3][r];
    *(short4*)&dst[b * ((long)D_MODEL * NKS) + (long)(d0 + r) * NKS + jj +
                   c * 16 + i * 4] = o;
  }
}

extern "C" void kernel_launch(void* const* d_in, const int* in_sizes, int n_in,
                              void* d_out, int out_size, void* d_ws,
                              size_t ws_size, hipStream_t stream)
{
  const float* Q = (const float*)d_in[0];
  const float* K = (const float*)d_in[1];
  const float* V = (const float*)d_in[2];
  const float* Wq = (const float*)d_in[3];
  const float* bq = (const float*)d_in[4];
  const float* Wk = (const float*)d_in[5];
  const float* bk = (const float*)d_in[6];
  const float* Wv = (const float*)d_in[7];
  const float* bv = (const float*)d_in[8];

  float* out = (float*)d_out;                         // [B,NQ,D] fp32
  float* attn = out + (long)BATCH * NQS * D_MODEL;    // [B,NQ,NK] fp32

  const long SZ = (long)BATCH * NQS * D_MODEL;        // 8388608 elements
  short* ws = (short*)d_ws;
  short* Qbf = ws;              // S0: bf16 Q        (dead after Qp GEMM)
  short* Kbf = ws + SZ;         // S1: bf16 K        (dead after Kp GEMM)
  short* Vbf = ws + 2 * SZ;     // S2: bf16 V        -> reused as Vpt
  short* Qp  = ws + 3 * SZ;     // S3: bf16 Qp
  short* pK  = ws + 4 * SZ;     // S4: bf16 Kp -> pK in place
  short* Vp  = ws + 5 * SZ;     // S5: bf16 Vp
  float* negent = (float*)(ws + 6 * SZ);              // [B*NK] fp32
  short* attn_bf = ws;          // S0+S1 reuse: bf16 attn [B,NQ,NK]
  short* Vpt = ws + 2 * SZ;     // S2 reuse: [B][D][NK]

  // bf16 weights live in d_out's attn region (dead until scores GEMM).
  short* Wqb = (short*)attn;
  short* Wkb = Wqb + (long)D_MODEL * D_MODEL;
  short* Wvb = Wkb + (long)D_MODEL * D_MODEL;

  dim3 blk(256);
  const int n8x = (int)(SZ / 8);                  // 1048576
  const int n8w = D_MODEL * D_MODEL / 8;          // 131072

  // 1) converts
  cvt_k<<<dim3(n8x / 256), blk, 0, stream>>>(Q, Qbf, n8x);
  cvt_k<<<dim3(n8x / 256), blk, 0, stream>>>(K, Kbf, n8x);
  cvt_k<<<dim3(n8x / 256), blk, 0, stream>>>(V, Vbf, n8x);
  cvt_k<<<dim3(n8w / 256), blk, 0, stream>>>(Wq, Wqb, n8w);
  cvt_k<<<dim3(n8w / 256), blk, 0, stream>>>(Wk, Wkb, n8w);
  cvt_k<<<dim3(n8w / 256), blk, 0, stream>>>(Wv, Wvb, n8w);

  // 2-4) projections: [8192,1024] x [1024,1024]^T -> bf16
  dim3 gp(D_MODEL / 128, (BATCH * NQS) / 128, 1);
  mfma_abt_k<<<gp, blk, 0, stream>>>(Qbf, Wqb, bq, 1.0f, nullptr, Qp,
                                     D_MODEL, D_MODEL, 0, 0, 0, 0);
  mfma_abt_k<<<gp, blk, 0, stream>>>(Kbf, Wkb, bk, 1.0f, nullptr, pK,
                                     D_MODEL, D_MODEL, 0, 0, 0, 0);
  mfma_abt_k<<<gp, blk, 0, stream>>>(Vbf, Wvb, bv, 1.0f, nullptr, Vp,
                                     D_MODEL, D_MODEL, 0, 0, 0, 0);

  // 5) Kp -> pK + negent
  kstats_k<<<dim3(BATCH * NKS), blk, 0, stream>>>(pK, negent);

  // 6) Vp -> Vpt
  transpose_k<<<dim3((BATCH * NKS) / 64, D_MODEL / 64), blk, 0, stream>>>(Vp,
                                                                          Vpt);

  // 7) scores = Qp·pK^T - negent[col]  -> attn fp32 (overwrites weights: ok)
  dim3 gs(NKS / 128, NQS / 128, BATCH);
  mfma_abt_k<<<gs, blk, 0, stream>>>(
      Qp, pK, negent, -1.0f, attn, nullptr, NKS, D_MODEL,
      (long)NQS * D_MODEL, (long)NKS * D_MODEL, (long)NQS * NKS, NKS);

  // 8) softmax rows -> attn fp32 (final output) + attn_bf
  asoftmax_k<<<dim3(BATCH * NQS), blk, 0, stream>>>(attn, attn_bf);

  // 9) out = attn_bf · Vpt^T  (= attn · Vp)
  dim3 go(D_MODEL / 128, NQS / 128, BATCH);
  mfma_abt_k<<<go, blk, 0, stream>>>(
      attn_bf, Vpt, nullptr, 0.f, out, nullptr, D_MODEL, NKS,
      (long)NQS * NKS, (long)D_MODEL * NKS, (long)NQS * D_MODEL, 0);
}

// Round 3
// 404.967 us; speedup vs baseline: 4.2549x; 1.0638x over previous
//
#include <hip/hip_runtime.h>
#include <math.h>

#define D_MODEL 1024
#define NQS 2048
#define NKS 2048
#define BATCH 4

typedef __attribute__((ext_vector_type(8))) short bf16x8;
typedef __attribute__((ext_vector_type(4))) float f32x4;

#define AS1 __attribute__((address_space(1)))
#define AS3 __attribute__((address_space(3)))

__device__ __forceinline__ unsigned short f2bf(float f) {
  unsigned u = __builtin_bit_cast(unsigned, f);
  u = (u + 0x7FFF + ((u >> 16) & 1)) >> 16;  // RNE
  return (unsigned short)u;
}
__device__ __forceinline__ float bf2f(unsigned short s) {
  return __builtin_bit_cast(float, ((unsigned)s) << 16);
}

// ---------------- fp32 -> bf16 converts (z-merged) ----------------
__global__ __launch_bounds__(256) void cvt3_k(
    const float* __restrict__ s0, const float* __restrict__ s1,
    const float* __restrict__ s2, short* __restrict__ d0,
    short* __restrict__ d1, short* __restrict__ d2, int n8)
{
  const int z = blockIdx.z;
  const float* src = z == 0 ? s0 : (z == 1 ? s1 : s2);
  short* dst = z == 0 ? d0 : (z == 1 ? d1 : d2);
  int i = blockIdx.x * 256 + threadIdx.x;
  if (i >= n8) return;
  const float4 a = *(const float4*)&src[(long)i * 8];
  const float4 b = *(const float4*)&src[(long)i * 8 + 4];
  bf16x8 o;
  o[0] = (short)f2bf(a.x); o[1] = (short)f2bf(a.y);
  o[2] = (short)f2bf(a.z); o[3] = (short)f2bf(a.w);
  o[4] = (short)f2bf(b.x); o[5] = (short)f2bf(b.y);
  o[6] = (short)f2bf(b.z); o[7] = (short)f2bf(b.w);
  *(bf16x8*)&dst[(long)i * 8] = o;
}

// ---------------- shared MFMA tile body: C = A*B^T (+bias*bscale) ---------
// A:[M,K] bf16 rm, B:[N,K] bf16 rm. 128x128 tile, 4 waves 2x2, BK=32.
__device__ __forceinline__ void gemm_tile_body(
    const short* __restrict__ Ab, const short* __restrict__ Bb,
    const float* __restrict__ bias, float bscale, float* __restrict__ Cf,
    short* __restrict__ Cbf, int N, int K)
{
  __shared__ short As[128 * 32];
  __shared__ short Bs[128 * 32];
  const int gm = blockIdx.y * 128, gn = blockIdx.x * 128;
  const int t = threadIdx.x;
  const int lane = t & 63, w = t >> 6;
  const int wm = w >> 1, wn = w & 1;

  const int srow = lane >> 2, sq = lane & 3;
  const short* ga0 = Ab + (long)(gm + w * 32 + srow) * K + sq * 8;
  const short* ga1 = Ab + (long)(gm + w * 32 + 16 + srow) * K + sq * 8;
  const short* gb0 = Bb + (long)(gn + w * 32 + srow) * K + sq * 8;
  const short* gb1 = Bb + (long)(gn + w * 32 + 16 + srow) * K + sq * 8;
  short* la0 = As + (w * 2 + 0) * 512;
  short* la1 = As + (w * 2 + 1) * 512;
  short* lb0 = Bs + (w * 2 + 0) * 512;
  short* lb1 = Bs + (w * 2 + 1) * 512;

  const int frow = lane & 15, fq = lane >> 4;

  f32x4 acc[4][4] = {};

  for (int k0 = 0; k0 < K; k0 += 32) {
    __builtin_amdgcn_global_load_lds((const AS1 void*)(ga0 + k0),
                                     (AS3 void*)la0, 16, 0, 0);
    __builtin_amdgcn_global_load_lds((const AS1 void*)(ga1 + k0),
                                     (AS3 void*)la1, 16, 0, 0);
    __builtin_amdgcn_global_load_lds((const AS1 void*)(gb0 + k0),
                                     (AS3 void*)lb0, 16, 0, 0);
    __builtin_amdgcn_global_load_lds((const AS1 void*)(gb1 + k0),
                                     (AS3 void*)lb1, 16, 0, 0);
    __syncthreads();
    bf16x8 af[4], bfm[4];
#pragma unroll
    for (int mi = 0; mi < 4; ++mi)
      af[mi] = *(const bf16x8*)&As[(wm * 64 + mi * 16 + frow) * 32 + fq * 8];
#pragma unroll
    for (int ni = 0; ni < 4; ++ni)
      bfm[ni] = *(const bf16x8*)&Bs[(wn * 64 + ni * 16 + frow) * 32 + fq * 8];
#pragma unroll
    for (int mi = 0; mi < 4; ++mi)
#pragma unroll
      for (int ni = 0; ni < 4; ++ni)
        acc[mi][ni] = __builtin_amdgcn_mfma_f32_16x16x32_bf16(
            af[mi], bfm[ni], acc[mi][ni], 0, 0, 0);
    __syncthreads();
  }

  float bb[4];
#pragma unroll
  for (int ni = 0; ni < 4; ++ni)
    bb[ni] = bias ? bias[gn + wn * 64 + ni * 16 + frow] * bscale : 0.f;

  // C/D layout: col = lane&15, row = (lane>>4)*4 + reg   [m89/m91]
#pragma unroll
  for (int mi = 0; mi < 4; ++mi) {
#pragma unroll
    for (int r = 0; r < 4; ++r) {
      const long row = gm + wm * 64 + mi * 16 + fq * 4 + r;
#pragma unroll
      for (int ni = 0; ni < 4; ++ni) {
        const long col = gn + wn * 64 + ni * 16 + frow;
        float v = acc[mi][ni][r] + bb[ni];
        if (Cf) Cf[row * (long)N + col] = v;
        else    Cbf[row * (long)N + col] = (short)f2bf(v);
      }
    }
  }
}

// Big GEMMs (scores, out): batched via z.
__global__ __launch_bounds__(256, 4) void mfma_abt_k(
    const short* __restrict__ A, const short* __restrict__ B,
    const float* __restrict__ bias, float bscale, float* __restrict__ Cf,
    short* __restrict__ Cbf, int N, int K, long sA, long sB, long sC,
    long sBias)
{
  const int bz = blockIdx.z;
  gemm_tile_body(A + (long)bz * sA, B + (long)bz * sB,
                 bias ? bias + (long)bz * sBias : nullptr, bscale,
                 Cf ? Cf + (long)bz * sC : nullptr,
                 Cbf ? Cbf + (long)bz * sC : nullptr, N, K);
}

// Projections: z selects (X, W, bias, dst). All [8192,1024]x[1024,1024]^T.
__global__ __launch_bounds__(256, 4) void mfma_proj_k(
    const short* __restrict__ Xq, const short* __restrict__ Xk,
    const short* __restrict__ Xv, const short* __restrict__ Wq,
    const short* __restrict__ Wk, const short* __restrict__ Wv,
    const float* __restrict__ bq, const float* __restrict__ bk,
    const float* __restrict__ bv, short* __restrict__ Oq,
    short* __restrict__ Ok, short* __restrict__ Ov)
{
  const int z = blockIdx.z;
  const short* X = z == 0 ? Xq : (z == 1 ? Xk : Xv);
  const short* W = z == 0 ? Wq : (z == 1 ? Wk : Wv);
  const float* bias = z == 0 ? bq : (z == 1 ? bk : bv);
  short* O = z == 0 ? Oq : (z == 1 ? Ok : Ov);
  gemm_tile_body(X, W, bias, 1.0f, nullptr, O, D_MODEL, D_MODEL);
}

// ---------------- K-stats: bf16 Kp row -> bf16 pK (in place) + negent -----
__global__ __launch_bounds__(256) void kstats_k(short* __restrict__ KP,
                                                float* __restrict__ negent)
{
  __shared__ float red[4];
  const long row = blockIdx.x;
  short* x = KP + row * (long)D_MODEL;
  const int t = threadIdx.x;
  short4 raw = *(const short4*)&x[t * 4];
  float v0 = bf2f((unsigned short)raw.x), v1 = bf2f((unsigned short)raw.y);
  float v2 = bf2f((unsigned short)raw.z), v3 = bf2f((unsigned short)raw.w);
  float m = fmaxf(fmaxf(v0, v1), fmaxf(v2, v3));
  for (int o = 32; o; o >>= 1) m = fmaxf(m, __shfl_xor(m, o));
  if ((t & 63) == 0) red[t >> 6] = m;
  __syncthreads();
  m = fmaxf(fmaxf(red[0], red[1]), fmaxf(red[2], red[3]));
  __syncthreads();
  float e0 = __expf(v0 - m), e1 = __expf(v1 - m), e2 = __expf(v2 - m),
        e3 = __expf(v3 - m);
  float s = e0 + e1 + e2 + e3;
  for (int o = 32; o; o >>= 1) s += __shfl_xor(s, o);
  if ((t & 63) == 0) red[t >> 6] = s;
  __syncthreads();
  s = red[0] + red[1] + red[2] + red[3];
  __syncthreads();
  const float inv = 1.0f / s;
  const float lse = m + __logf(s);
  float p0 = e0 * inv, p1 = e1 * inv, p2 = e2 * inv, p3 = e3 * inv;
  float ne = p0 * (v0 - lse) + p1 * (v1 - lse) + p2 * (v2 - lse) +
             p3 * (v3 - lse);
  for (int o = 32; o; o >>= 1) ne += __shfl_xor(ne, o);
  if ((t & 63) == 0) red[t >> 6] = ne;
  __syncthreads();
  if (t == 0) negent[row] = red[0] + red[1] + red[2] + red[3];
  short4 pw;
  pw.x = (short)f2bf(p0); pw.y = (short)f2bf(p1);
  pw.z = (short)f2bf(p2); pw.w = (short)f2bf(p3);
  *(short4*)&x[t * 4] = pw;
}

// ---------------- attn softmax: fp32 in place + bf16 copy -----------------
__global__ __launch_bounds__(256) void asoftmax_k(float* __restrict__ S,
                                                  short* __restrict__ Sbf)
{
  __shared__ float red[4];
  const long row = blockIdx.x;
  float* x = S + row * (long)NKS;
  short* y = Sbf + row * (long)NKS;
  const int t = threadIdx.x;
  float4 v0 = *(const float4*)&x[t * 4];
  float4 v1 = *(const float4*)&x[1024 + t * 4];
  float m = fmaxf(fmaxf(fmaxf(v0.x, v0.y), fmaxf(v0.z, v0.w)),
                  fmaxf(fmaxf(v1.x, v1.y), fmaxf(v1.z, v1.w)));
  for (int o = 32; o; o >>= 1) m = fmaxf(m, __shfl_xor(m, o));
  if ((t & 63) == 0) red[t >> 6] = m;
  __syncthreads();
  m = fmaxf(fmaxf(red[0], red[1]), fmaxf(red[2], red[3]));
  __syncthreads();
  float4 e0 = {__expf(v0.x - m), __expf(v0.y - m), __expf(v0.z - m),
               __expf(v0.w - m)};
  float4 e1 = {__expf(v1.x - m), __expf(v1.y - m), __expf(v1.z - m),
               __expf(v1.w - m)};
  float s = e0.x + e0.y + e0.z + e0.w + e1.x + e1.y + e1.z + e1.w;
  for (int o = 32; o; o >>= 1) s += __shfl_xor(s, o);
  if ((t & 63) == 0) red[t >> 6] = s;
  __syncthreads();
  s = red[0] + red[1] + red[2] + red[3];
  const float inv = 1.0f / s;
  float4 p0 = {e0.x * inv, e0.y * inv, e0.z * inv, e0.w * inv};
  float4 p1 = {e1.x * inv, e1.y * inv, e1.z * inv, e1.w * inv};
  *(float4*)&x[t * 4] = p0;
  *(float4*)&x[1024 + t * 4] = p1;
  short4 b0, b1;
  b0.x = (short)f2bf(p0.x); b0.y = (short)f2bf(p0.y);
  b0.z = (short)f2bf(p0.z); b0.w = (short)f2bf(p0.w);
  b1.x = (short)f2bf(p1.x); b1.y = (short)f2bf(p1.y);
  b1.z = (short)f2bf(p1.z); b1.w = (short)f2bf(p1.w);
  *(short4*)&y[t * 4] = b0;
  *(short4*)&y[1024 + t * 4] = b1;
}

// ---------------- Vp [8192,1024] -> Vpt [B][1024][2048] transpose ---------
__global__ __launch_bounds__(256) void transpose_k(const short* __restrict__ src,
                                                   short* __restrict__ dst)
{
  __shared__ short tile[64][68];
  const int j0 = blockIdx.x * 64;
  const int d0 = blockIdx.y * 64;
  const int t = threadIdx.x;
  const int r = t >> 2, c = t & 3;
#pragma unroll
  for (int i = 0; i < 4; ++i)
    *(short4*)&tile[r][c * 16 + i * 4] =
        *(const short4*)&src[(long)(j0 + r) * D_MODEL + d0 + c * 16 + i * 4];
  __syncthreads();
  const long b = j0 >> 11;
  const int jj = j0 & 2047;
#pragma unroll
  for (int i = 0; i < 4; ++i) {
    short4 o;
    o.x = tile[c * 16 + i * 4 + 0][r];
    o.y = tile[c * 16 + i * 4 + 1][r];
    o.z = tile[c * 16 + i * 4 + 2][r];
    o.w = tile[c * 16 + i * 4 + 3][r];
    *(short4*)&dst[b * ((long)D_MODEL * NKS) + (long)(d0 + r) * NKS + jj +
                   c * 16 + i * 4] = o;
  }
}

extern "C" void kernel_launch(void* const* d_in, const int* in_sizes, int n_in,
                              void* d_out, int out_size, void* d_ws,
                              size_t ws_size, hipStream_t stream)
{
  const float* Q = (const float*)d_in[0];
  const float* K = (const float*)d_in[1];
  const float* V = (const float*)d_in[2];
  const float* Wq = (const float*)d_in[3];
  const float* bq = (const float*)d_in[4];
  const float* Wk = (const float*)d_in[5];
  const float* bk = (const float*)d_in[6];
  const float* Wv = (const float*)d_in[7];
  const float* bv = (const float*)d_in[8];

  float* out = (float*)d_out;                         // [B,NQ,D] fp32
  float* attn = out + (long)BATCH * NQS * D_MODEL;    // [B,NQ,NK] fp32

  const long SZ = (long)BATCH * NQS * D_MODEL;        // 8388608 elements
  short* ws = (short*)d_ws;
  short* Qbf = ws;              // S0 (dead after proj) -> attn_bf low half
  short* Kbf = ws + SZ;         // S1 (dead after proj) -> attn_bf high half
  short* Vbf = ws + 2 * SZ;     // S2 (dead after proj) -> Vpt
  short* Qp  = ws + 3 * SZ;     // S3
  short* pK  = ws + 4 * SZ;     // S4 (Kp -> pK in place)
  short* Vp  = ws + 5 * SZ;     // S5
  float* negent = (float*)(ws + 6 * SZ);              // [B*NK] fp32
  short* attn_bf = ws;          // S0+S1 reuse
  short* Vpt = ws + 2 * SZ;     // S2 reuse: [B][D][NK]

  // bf16 weights live in d_out's attn region (dead until scores GEMM).
  short* Wqb = (short*)attn;
  short* Wkb = Wqb + (long)D_MODEL * D_MODEL;
  short* Wvb = Wkb + (long)D_MODEL * D_MODEL;

  dim3 blk(256);
  const int n8x = (int)(SZ / 8);                  // 1048576
  const int n8w = D_MODEL * D_MODEL / 8;          // 131072

  // 1) converts (2 dispatches)
  cvt3_k<<<dim3(n8x / 256, 1, 3), blk, 0, stream>>>(Q, K, V, Qbf, Kbf, Vbf,
                                                    n8x);
  cvt3_k<<<dim3(n8w / 256, 1, 3), blk, 0, stream>>>(Wq, Wk, Wv, Wqb, Wkb, Wvb,
                                                    n8w);

  // 2) projections, one dispatch: grid (8, 64, 3)
  dim3 gp(D_MODEL / 128, (BATCH * NQS) / 128, 3);
  mfma_proj_k<<<gp, blk, 0, stream>>>(Qbf, Kbf, Vbf, Wqb, Wkb, Wvb, bq, bk,
                                      bv, Qp, pK, Vp);

  // 3) Kp -> pK + negent
  kstats_k<<<dim3(BATCH * NKS), blk, 0, stream>>>(pK, negent);

  // 4) Vp -> Vpt
  transpose_k<<<dim3((BATCH * NKS) / 64, D_MODEL / 64), blk, 0, stream>>>(Vp,
                                                                          Vpt);

  // 5) scores = Qp·pK^T - negent[col]  -> attn fp32
  dim3 gs(NKS / 128, NQS / 128, BATCH);
  mfma_abt_k<<<gs, blk, 0, stream>>>(
      Qp, pK, negent, -1.0f, attn, nullptr, NKS, D_MODEL,
      (long)NQS * D_MODEL, (long)NKS * D_MODEL, (long)NQS * NKS, NKS);

  // 6) attn = softmax(scores) fp32 in place + bf16 copy
  asoftmax_k<<<dim3(BATCH * NQS), blk, 0, stream>>>(attn, attn_bf);

  // 7) out = attn_bf · Vpt^T  (= attn · Vp)
  dim3 go(D_MODEL / 128, NQS / 128, BATCH);
  mfma_abt_k<<<go, blk, 0, stream>>>(
      attn_bf, Vpt, nullptr, 0.f, out, nullptr, D_MODEL, NKS,
      (long)NQS * NKS, (long)D_MODEL * NKS, (long)NQS * D_MODEL, 0);
}

// Round 5
// 378.794 us; speedup vs baseline: 4.5489x; 1.0691x over previous
//
#include <hip/hip_runtime.h>
#include <math.h>

#define D_MODEL 1024
#define NQS 2048
#define NKS 2048
#define BATCH 4

typedef __attribute__((ext_vector_type(8))) short bf16x8;
typedef __attribute__((ext_vector_type(4))) float f32x4;

#define AS1 __attribute__((address_space(1)))
#define AS3 __attribute__((address_space(3)))

__device__ __forceinline__ unsigned short f2bf(float f) {
  unsigned u = __builtin_bit_cast(unsigned, f);
  u = (u + 0x7FFF + ((u >> 16) & 1)) >> 16;  // RNE
  return (unsigned short)u;
}
__device__ __forceinline__ float bf2f(unsigned short s) {
  return __builtin_bit_cast(float, ((unsigned)s) << 16);
}

// ---------------- fp32 -> bf16 converts (z-merged) ----------------
__global__ __launch_bounds__(256) void cvt3_k(
    const float* __restrict__ s0, const float* __restrict__ s1,
    const float* __restrict__ s2, short* __restrict__ d0,
    short* __restrict__ d1, short* __restrict__ d2, int n8)
{
  const int z = blockIdx.z;
  const float* src = z == 0 ? s0 : (z == 1 ? s1 : s2);
  short* dst = z == 0 ? d0 : (z == 1 ? d1 : d2);
  int i = blockIdx.x * 256 + threadIdx.x;
  if (i >= n8) return;
  const float4 a = *(const float4*)&src[(long)i * 8];
  const float4 b = *(const float4*)&src[(long)i * 8 + 4];
  bf16x8 o;
  o[0] = (short)f2bf(a.x); o[1] = (short)f2bf(a.y);
  o[2] = (short)f2bf(a.z); o[3] = (short)f2bf(a.w);
  o[4] = (short)f2bf(b.x); o[5] = (short)f2bf(b.y);
  o[6] = (short)f2bf(b.z); o[7] = (short)f2bf(b.w);
  *(bf16x8*)&dst[(long)i * 8] = o;
}

// ---------------- shared MFMA tile body: C = A*B^T (+bias*bscale) ---------
// A:[M,K] bf16 rm, B:[N,K] bf16 rm. 128x128 tile, 4 waves 2x2, BK=64 as two
// 32-col panels (each panel = the verified m97 layout). gm/gn from caller.
__device__ __forceinline__ void gemm_tile_body(
    const short* __restrict__ Ab, const short* __restrict__ Bb,
    const float* __restrict__ bias, float bscale, float* __restrict__ Cf,
    short* __restrict__ Cbf, int N, int K, int gm, int gn)
{
  __shared__ short As[2][128 * 32];
  __shared__ short Bs[2][128 * 32];
  const int t = threadIdx.x;
  const int lane = t & 63, w = t >> 6;
  const int wm = w >> 1, wn = w & 1;

  // staging: per 32-col panel, wave fills 2 segments (16 rows x 64 B) for A
  // and B. LDS dest is wave-uniform base + lane*16 B (m104/m108 rule).
  const int srow = lane >> 2, sq = lane & 3;
  const short* gA0 = Ab + (long)(gm + w * 32 + srow) * K + sq * 8;
  const short* gA1 = Ab + (long)(gm + w * 32 + 16 + srow) * K + sq * 8;
  const short* gB0 = Bb + (long)(gn + w * 32 + srow) * K + sq * 8;
  const short* gB1 = Bb + (long)(gn + w * 32 + 16 + srow) * K + sq * 8;
  const int seg0 = (w * 2 + 0) * 512, seg1 = (w * 2 + 1) * 512;

  const int frow = lane & 15, fq = lane >> 4;

  f32x4 acc[4][4] = {};

  for (int k0 = 0; k0 < K; k0 += 64) {
#pragma unroll
    for (int p = 0; p < 2; ++p) {
      const int ko = k0 + p * 32;
      __builtin_amdgcn_global_load_lds((const AS1 void*)(gA0 + ko),
                                       (AS3 void*)(&As[p][seg0]), 16, 0, 0);
      __builtin_amdgcn_global_load_lds((const AS1 void*)(gA1 + ko),
                                       (AS3 void*)(&As[p][seg1]), 16, 0, 0);
      __builtin_amdgcn_global_load_lds((const AS1 void*)(gB0 + ko),
                                       (AS3 void*)(&Bs[p][seg0]), 16, 0, 0);
      __builtin_amdgcn_global_load_lds((const AS1 void*)(gB1 + ko),
                                       (AS3 void*)(&Bs[p][seg1]), 16, 0, 0);
    }
    __syncthreads();
#pragma unroll
    for (int p = 0; p < 2; ++p) {
      bf16x8 af[4], bfm[4];
#pragma unroll
      for (int mi = 0; mi < 4; ++mi)
        af[mi] =
            *(const bf16x8*)&As[p][(wm * 64 + mi * 16 + frow) * 32 + fq * 8];
#pragma unroll
      for (int ni = 0; ni < 4; ++ni)
        bfm[ni] =
            *(const bf16x8*)&Bs[p][(wn * 64 + ni * 16 + frow) * 32 + fq * 8];
#pragma unroll
      for (int mi = 0; mi < 4; ++mi)
#pragma unroll
        for (int ni = 0; ni < 4; ++ni)
          acc[mi][ni] = __builtin_amdgcn_mfma_f32_16x16x32_bf16(
              af[mi], bfm[ni], acc[mi][ni], 0, 0, 0);
    }
    __syncthreads();
  }

  float bb[4];
#pragma unroll
  for (int ni = 0; ni < 4; ++ni)
    bb[ni] = bias ? bias[gn + wn * 64 + ni * 16 + frow] * bscale : 0.f;

  // C/D layout: col = lane&15, row = (lane>>4)*4 + reg   [m89/m91]
#pragma unroll
  for (int mi = 0; mi < 4; ++mi) {
#pragma unroll
    for (int r = 0; r < 4; ++r) {
      const long row = gm + wm * 64 + mi * 16 + fq * 4 + r;
#pragma unroll
      for (int ni = 0; ni < 4; ++ni) {
        const long col = gn + wn * 64 + ni * 16 + frow;
        float v = acc[mi][ni][r] + bb[ni];
        if (Cf) Cf[row * (long)N + col] = v;
        else    Cbf[row * (long)N + col] = (short)f2bf(v);
      }
    }
  }
}

// Batched big GEMMs. swap==0: gn from x (n-major, scores). swap==1: gm from
// x (m-major — same-A-slab blocks land on the same XCD; out-GEMM).
__global__ __launch_bounds__(256, 4) void mfma_abt_k(
    const short* __restrict__ A, const short* __restrict__ B,
    const float* __restrict__ bias, float bscale, float* __restrict__ Cf,
    short* __restrict__ Cbf, int N, int K, long sA, long sB, long sC,
    long sBias, int swap)
{
  const int bz = blockIdx.z;
  const int gm = (swap ? blockIdx.x : blockIdx.y) * 128;
  const int gn = (swap ? blockIdx.y : blockIdx.x) * 128;
  gemm_tile_body(A + (long)bz * sA, B + (long)bz * sB,
                 bias ? bias + (long)bz * sBias : nullptr, bscale,
                 Cf ? Cf + (long)bz * sC : nullptr,
                 Cbf ? Cbf + (long)bz * sC : nullptr, N, K, gm, gn);
}

// Projections, m-major: grid (64, 8, 3); z selects (X, W, bias, dst).
__global__ __launch_bounds__(256, 4) void mfma_proj_k(
    const short* __restrict__ Xq, const short* __restrict__ Xk,
    const short* __restrict__ Xv, const short* __restrict__ Wq,
    const short* __restrict__ Wk, const short* __restrict__ Wv,
    const float* __restrict__ bq, const float* __restrict__ bk,
    const float* __restrict__ bv, short* __restrict__ Oq,
    short* __restrict__ Ok, short* __restrict__ Ov)
{
  const int z = blockIdx.z;
  const short* X = z == 0 ? Xq : (z == 1 ? Xk : Xv);
  const short* W = z == 0 ? Wq : (z == 1 ? Wk : Wv);
  const float* bias = z == 0 ? bq : (z == 1 ? bk : bv);
  short* O = z == 0 ? Oq : (z == 1 ? Ok : Ov);
  gemm_tile_body(X, W, bias, 1.0f, nullptr, O, D_MODEL, D_MODEL,
                 blockIdx.x * 128, blockIdx.y * 128);
}

// ---------------- K-stats: bf16 Kp row -> bf16 pK (in place) + negent -----
__global__ __launch_bounds__(256) void kstats_k(short* __restrict__ KP,
                                                float* __restrict__ negent)
{
  __shared__ float red[4];
  const long row = blockIdx.x;
  short* x = KP + row * (long)D_MODEL;
  const int t = threadIdx.x;
  short4 raw = *(const short4*)&x[t * 4];
  float v0 = bf2f((unsigned short)raw.x), v1 = bf2f((unsigned short)raw.y);
  float v2 = bf2f((unsigned short)raw.z), v3 = bf2f((unsigned short)raw.w);
  float m = fmaxf(fmaxf(v0, v1), fmaxf(v2, v3));
  for (int o = 32; o; o >>= 1) m = fmaxf(m, __shfl_xor(m, o));
  if ((t & 63) == 0) red[t >> 6] = m;
  __syncthreads();
  m = fmaxf(fmaxf(red[0], red[1]), fmaxf(red[2], red[3]));
  __syncthreads();
  float e0 = __expf(v0 - m), e1 = __expf(v1 - m), e2 = __expf(v2 - m),
        e3 = __expf(v3 - m);
  float s = e0 + e1 + e2 + e3;
  for (int o = 32; o; o >>= 1) s += __shfl_xor(s, o);
  if ((t & 63) == 0) red[t >> 6] = s;
  __syncthreads();
  s = red[0] + red[1] + red[2] + red[3];
  __syncthreads();
  const float inv = 1.0f / s;
  const float lse = m + __logf(s);
  float p0 = e0 * inv, p1 = e1 * inv, p2 = e2 * inv, p3 = e3 * inv;
  float ne = p0 * (v0 - lse) + p1 * (v1 - lse) + p2 * (v2 - lse) +
             p3 * (v3 - lse);
  for (int o = 32; o; o >>= 1) ne += __shfl_xor(ne, o);
  if ((t & 63) == 0) red[t >> 6] = ne;
  __syncthreads();
  if (t == 0) negent[row] = red[0] + red[1] + red[2] + red[3];
  short4 pw;
  pw.x = (short)f2bf(p0); pw.y = (short)f2bf(p1);
  pw.z = (short)f2bf(p2); pw.w = (short)f2bf(p3);
  *(short4*)&x[t * 4] = pw;
}

// ---------------- attn softmax: fp32 in place + bf16 copy -----------------
__global__ __launch_bounds__(256) void asoftmax_k(float* __restrict__ S,
                                                  short* __restrict__ Sbf)
{
  __shared__ float red[4];
  const long row = blockIdx.x;
  float* x = S + row * (long)NKS;
  short* y = Sbf + row * (long)NKS;
  const int t = threadIdx.x;
  float4 v0 = *(const float4*)&x[t * 4];
  float4 v1 = *(const float4*)&x[1024 + t * 4];
  float m = fmaxf(fmaxf(fmaxf(v0.x, v0.y), fmaxf(v0.z, v0.w)),
                  fmaxf(fmaxf(v1.x, v1.y), fmaxf(v1.z, v1.w)));
  for (int o = 32; o; o >>= 1) m = fmaxf(m, __shfl_xor(m, o));
  if ((t & 63) == 0) red[t >> 6] = m;
  __syncthreads();
  m = fmaxf(fmaxf(red[0], red[1]), fmaxf(red[2], red[3]));
  __syncthreads();
  float4 e0 = {__expf(v0.x - m), __expf(v0.y - m), __expf(v0.z - m),
               __expf(v0.w - m)};
  float4 e1 = {__expf(v1.x - m), __expf(v1.y - m), __expf(v1.z - m),
               __expf(v1.w - m)};
  float s = e0.x + e0.y + e0.z + e0.w + e1.x + e1.y + e1.z + e1.w;
  for (int o = 32; o; o >>= 1) s += __shfl_xor(s, o);
  if ((t & 63) == 0) red[t >> 6] = s;
  __syncthreads();
  s = red[0] + red[1] + red[2] + red[3];
  const float inv = 1.0f / s;
  float4 p0 = {e0.x * inv, e0.y * inv, e0.z * inv, e0.w * inv};
  float4 p1 = {e1.x * inv, e1.y * inv, e1.z * inv, e1.w * inv};
  *(float4*)&x[t * 4] = p0;
  *(float4*)&x[1024 + t * 4] = p1;
  short4 b0, b1;
  b0.x = (short)f2bf(p0.x); b0.y = (short)f2bf(p0.y);
  b0.z = (short)f2bf(p0.z); b0.w = (short)f2bf(p0.w);
  b1.x = (short)f2bf(p1.x); b1.y = (short)f2bf(p1.y);
  b1.z = (short)f2bf(p1.z); b1.w = (short)f2bf(p1.w);
  *(short4*)&y[t * 4] = b0;
  *(short4*)&y[1024 + t * 4] = b1;
}

// ---------------- Vp [8192,1024] -> Vpt [B][1024][2048] transpose ---------
__global__ __launch_bounds__(256) void transpose_k(const short* __restrict__ src,
                                                   short* __restrict__ dst)
{
  __shared__ short tile[64][68];
  const int j0 = blockIdx.x * 64;
  const int d0 = blockIdx.y * 64;
  const int t = threadIdx.x;
  const int r = t >> 2, c = t & 3;
#pragma unroll
  for (int i = 0; i < 4; ++i)
    *(short4*)&tile[r][c * 16 + i * 4] =
        *(const short4*)&src[(long)(j0 + r) * D_MODEL + d0 + c * 16 + i * 4];
  __syncthreads();
  const long b = j0 >> 11;
  const int jj = j0 & 2047;
#pragma unroll
  for (int i = 0; i < 4; ++i) {
    short4 o;
    o.x = tile[c * 16 + i * 4 + 0][r];
    o.y = tile[c * 16 + i * 4 + 1][r];
    o.z = tile[c * 16 + i * 4 + 2][r];
    o.w = tile[c * 16 + i * 4 + 3][r];
    *(short4*)&dst[b * ((long)D_MODEL * NKS) + (long)(d0 + r) * NKS + jj +
                   c * 16 + i * 4] = o;
  }
}

extern "C" void kernel_launch(void* const* d_in, const int* in_sizes, int n_in,
                              void* d_out, int out_size, void* d_ws,
                              size_t ws_size, hipStream_t stream)
{
  const float* Q = (const float*)d_in[0];
  const float* K = (const float*)d_in[1];
  const float* V = (const float*)d_in[2];
  const float* Wq = (const float*)d_in[3];
  const float* bq = (const float*)d_in[4];
  const float* Wk = (const float*)d_in[5];
  const float* bk = (const float*)d_in[6];
  const float* Wv = (const float*)d_in[7];
  const float* bv = (const float*)d_in[8];

  float* out = (float*)d_out;                         // [B,NQ,D] fp32
  float* attn = out + (long)BATCH * NQS * D_MODEL;    // [B,NQ,NK] fp32

  const long SZ = (long)BATCH * NQS * D_MODEL;        // 8388608 elements
  short* ws = (short*)d_ws;
  short* Qbf = ws;              // S0 (dead after proj) -> attn_bf low half
  short* Kbf = ws + SZ;         // S1 (dead after proj) -> attn_bf high half
  short* Vbf = ws + 2 * SZ;     // S2 (dead after proj) -> Vpt
  short* Qp  = ws + 3 * SZ;     // S3
  short* pK  = ws + 4 * SZ;     // S4 (Kp -> pK in place)
  short* Vp  = ws + 5 * SZ;     // S5
  float* negent = (float*)(ws + 6 * SZ);              // [B*NK] fp32
  short* attn_bf = ws;          // S0+S1 reuse
  short* Vpt = ws + 2 * SZ;     // S2 reuse: [B][D][NK]

  // bf16 weights live in d_out's attn region (dead until scores GEMM).
  short* Wqb = (short*)attn;
  short* Wkb = Wqb + (long)D_MODEL * D_MODEL;
  short* Wvb = Wkb + (long)D_MODEL * D_MODEL;

  dim3 blk(256);
  const int n8x = (int)(SZ / 8);                  // 1048576
  const int n8w = D_MODEL * D_MODEL / 8;          // 131072

  // 1) converts (2 dispatches)
  cvt3_k<<<dim3(n8x / 256, 1, 3), blk, 0, stream>>>(Q, K, V, Qbf, Kbf, Vbf,
                                                    n8x);
  cvt3_k<<<dim3(n8w / 256, 1, 3), blk, 0, stream>>>(Wq, Wk, Wv, Wqb, Wkb, Wvb,
                                                    n8w);

  // 2) projections, m-major: grid (64, 8, 3)
  dim3 gp((BATCH * NQS) / 128, D_MODEL / 128, 3);
  mfma_proj_k<<<gp, blk, 0, stream>>>(Qbf, Kbf, Vbf, Wqb, Wkb, Wvb, bq, bk,
                                      bv, Qp, pK, Vp);

  // 3) Kp -> pK + negent
  kstats_k<<<dim3(BATCH * NKS), blk, 0, stream>>>(pK, negent);

  // 4) Vp -> Vpt
  transpose_k<<<dim3((BATCH * NKS) / 64, D_MODEL / 64), blk, 0, stream>>>(Vp,
                                                                          Vpt);

  // 5) scores = Qp·pK^T - negent[col] -> attn fp32 (n-major: near-ideal L3)
  dim3 gs(NKS / 128, NQS / 128, BATCH);
  mfma_abt_k<<<gs, blk, 0, stream>>>(
      Qp, pK, negent, -1.0f, attn, nullptr, NKS, D_MODEL,
      (long)NQS * D_MODEL, (long)NKS * D_MODEL, (long)NQS * NKS, NKS, 0);

  // 6) attn = softmax(scores) fp32 in place + bf16 copy
  asoftmax_k<<<dim3(BATCH * NQS), blk, 0, stream>>>(attn, attn_bf);

  // 7) out = attn_bf · Vpt^T, m-major: grid (16, 8, 4)
  dim3 go(NQS / 128, D_MODEL / 128, BATCH);
  mfma_abt_k<<<go, blk, 0, stream>>>(
      attn_bf, Vpt, nullptr, 0.f, out, nullptr, D_MODEL, NKS,
      (long)NQS * NKS, (long)D_MODEL * NKS, (long)NQS * D_MODEL, 0, 1);
}